// Round 9
// baseline (331.796 us; speedup 1.0000x reference)
//
#include <hip/hip_runtime.h>

#define NB 4
#define CC 512
#define NSP 4096
#define NGRP 32

using bf16x8 = __attribute__((ext_vector_type(8))) __bf16;
using f32x4  = __attribute__((ext_vector_type(4))) float;

__device__ __forceinline__ unsigned short f2bf(float f) {
  union { float f; unsigned int u; } v; v.f = f;
  unsigned int r = v.u + 0x7fffu + ((v.u >> 16) & 1u);
  return (unsigned short)(r >> 16);
}
__device__ __forceinline__ float bf2f(unsigned short h) {
  union { unsigned int u; float f; } v; v.u = ((unsigned int)h) << 16;
  return v.f;
}

// ---------------- weights fp32 -> bf16; wq pre-scaled; bias_qk built ----------------
__global__ __launch_bounds__(256) void cvt_w_kernel(const float* __restrict__ wq,
    const float* __restrict__ wk, const float* __restrict__ wv,
    const float* __restrict__ wo, const float* __restrict__ bq,
    const float* __restrict__ bk, unsigned short* __restrict__ wqk,
    unsigned short* __restrict__ wv_bf, unsigned short* __restrict__ wo_bf,
    float* __restrict__ bias_qk, float scale) {
  int i = blockIdx.x * 256 + threadIdx.x;  // covers 512*512
  wqk[i]          = f2bf(wq[i] * scale);   // rows 0..511: scaled q weights
  wqk[i + 262144] = f2bf(wk[i]);           // rows 512..1023: k weights
  wv_bf[i] = f2bf(wv[i]);
  wo_bf[i] = f2bf(wo[i]);
  if (i < 512)        bias_qk[i] = bq[i] * scale;
  else if (i < 1024)  bias_qk[i] = bk[i - 512];
}

// ---------------- fused GroupNorm: stats + apply + transpose ----------------
// one block per (b,g); writes xnT[b][n][g*16 .. g*16+15]
__global__ __launch_bounds__(256) void gn_kernel(const float* __restrict__ x,
    const float* __restrict__ gw, const float* __restrict__ gb,
    unsigned short* __restrict__ xnT) {
  const int b = blockIdx.x >> 5, g = blockIdx.x & 31;
  const int tid = threadIdx.x;
  const float* xb = x + ((size_t)b * CC + g * 16) * NSP;  // 16 x 4096
  // ---- stats ----
  const float4* p = reinterpret_cast<const float4*>(xb);
  float s = 0.f, ss = 0.f;
  for (int i = tid; i < 16384; i += 256) {
    float4 v = p[i];
    s  += v.x + v.y + v.z + v.w;
    ss += v.x * v.x + v.y * v.y + v.z * v.z + v.w * v.w;
  }
  __shared__ float rs[4], rss[4], mr[2];
  #pragma unroll
  for (int o = 32; o >= 1; o >>= 1) { s += __shfl_down(s, o); ss += __shfl_down(ss, o); }
  if ((tid & 63) == 0) { rs[tid >> 6] = s; rss[tid >> 6] = ss; }
  __syncthreads();
  if (tid == 0) {
    s = rs[0] + rs[1] + rs[2] + rs[3];
    ss = rss[0] + rss[1] + rss[2] + rss[3];
    float mean = s * (1.f / 65536.f);
    float var = ss * (1.f / 65536.f) - mean * mean;
    mr[0] = mean; mr[1] = rsqrtf(var + 1e-6f);
  }
  __syncthreads();
  const float mean = mr[0], rstd = mr[1];
  // ---- apply + transpose, 64-col tiles ----
  __shared__ unsigned short tile[16][72];
  const int cl = tid >> 4;            // load: channel 0..15
  const int nq = tid & 15;            // load: n-offset group
  const float sc = rstd * gw[g * 16 + cl];
  const float shv = gb[g * 16 + cl] - mean * sc;
  const int n_l = tid >> 2;           // store: n 0..63
  const int c4 = (tid & 3) * 4;       // store: channel quad
  unsigned short* xout = xnT + (size_t)b * NSP * CC + g * 16;
  #pragma unroll 1
  for (int t16 = 0; t16 < 64; ++t16) {
    const int n0 = t16 * 64;
    float4 v = *reinterpret_cast<const float4*>(xb + (size_t)cl * NSP + n0 + nq * 4);
    ushort4 w;
    w.x = f2bf(v.x * sc + shv); w.y = f2bf(v.y * sc + shv);
    w.z = f2bf(v.z * sc + shv); w.w = f2bf(v.w * sc + shv);
    *reinterpret_cast<ushort4*>(&tile[cl][nq * 4]) = w;
    __syncthreads();
    ushort4 o;
    o.x = tile[c4 + 0][n_l]; o.y = tile[c4 + 1][n_l];
    o.z = tile[c4 + 2][n_l]; o.w = tile[c4 + 3][n_l];
    *reinterpret_cast<ushort4*>(xout + (size_t)(n0 + n_l) * CC + c4) = o;
    __syncthreads();
  }
}

// ---------------- sum 64 partials -> 1/l per row ----------------
__global__ __launch_bounds__(256) void sum_reduce_kernel(const float* __restrict__ part,
                                                         float* __restrict__ invl) {
  const int row = blockIdx.x * 4 + (threadIdx.x >> 6);
  const int lane = threadIdx.x & 63;
  float v = part[((size_t)row << 6) + lane];
  #pragma unroll
  for (int msk = 1; msk <= 32; msk <<= 1) v += __shfl_xor(v, msk);
  if (lane == 0) invl[row] = 1.f / v;
}

// ---------------- 128^2 MFMA GEMM: dbuf + counted vmcnt + swizzled LDS + XCD swizzle ----
// C[M,N] = A[M,K].B[N,K]^T (row strides lda/ldb). BIAS 0/1(row)/2(col); OBF16; RESID.
// EXPOUT: C=exp(min(acc*scale,80)) bf16 + per-row 64-col partial sums.
// INVL: epilogue multiplies by invl_in[row]. SQCH: square XCD chunking (grid 32x32x4 only).
template<int BIAS, bool OBF16, bool RESID, bool EXPOUT, bool INVL, bool SQCH>
__global__ __launch_bounds__(256) void gemm2(
    const unsigned short* __restrict__ A, const unsigned short* __restrict__ B,
    const float* __restrict__ bias, const float* __restrict__ resid,
    void* __restrict__ Cout, const float* __restrict__ invl_in,
    float* __restrict__ part_out, int M, int N, int K, int lda, int ldb, float scale,
    long long sAb, long long sBb, long long sCb, long long sRb) {
  __shared__ __align__(16) unsigned short sA[2][128 * 64];
  __shared__ __align__(16) unsigned short sB[2][128 * 64];
  const int tid = threadIdx.x;
  const int lane = tid & 63;
  const int wid  = tid >> 6;

  int bn, bm, b;
  if constexpr (SQCH) {
    // grid fixed 32x32x4: XCD chunk = 16x8 (bm,bn) rectangle per batch
    unsigned lin = blockIdx.x + 32 * (blockIdx.y + 32 * blockIdx.z);
    lin = (lin & 7) * 512 + (lin >> 3);
    b = lin & 3;
    const unsigned u = lin >> 2, q = u >> 7, r = u & 127;
    bm = ((q & 1) << 4) | (r & 15);
    bn = ((q >> 1) << 3) | (r >> 4);
  } else {
    const unsigned nwg = gridDim.x * gridDim.y * gridDim.z;
    unsigned lin = blockIdx.x + gridDim.x * (blockIdx.y + gridDim.y * blockIdx.z);
    lin = (lin & 7) * (nwg >> 3) + (lin >> 3);
    bn = lin % gridDim.x;
    const unsigned t2 = lin / gridDim.x;
    bm = t2 % gridDim.y;
    b  = t2 / gridDim.y;
  }

  const unsigned short* Ab = A + (size_t)b * sAb + (size_t)bm * 128 * lda;
  const unsigned short* Bb = B + (size_t)b * sBb + (size_t)bn * 128 * ldb;
  const int wm = wid >> 1, wn = wid & 1;
  const int l15 = lane & 15, h = lane >> 4;

  f32x4 acc[4][4] = {};

  auto stage = [&](int buf, int k0) {
    #pragma unroll
    for (int it = 0; it < 4; ++it) {
      const int o  = (it * 256 + tid) * 16;
      const int r  = o >> 7;
      const int c2 = (o & 127) ^ ((r & 7) << 4);
      __builtin_amdgcn_global_load_lds(
          (const __attribute__((address_space(1))) void*)((const char*)(Ab + (size_t)r * lda + k0) + c2),
          (__attribute__((address_space(3))) void*)((char*)sA[buf] + o), 16, 0, 0);
      __builtin_amdgcn_global_load_lds(
          (const __attribute__((address_space(1))) void*)((const char*)(Bb + (size_t)r * ldb + k0) + c2),
          (__attribute__((address_space(3))) void*)((char*)sB[buf] + o), 16, 0, 0);
    }
  };

  int abase[4], bbase[4];
  #pragma unroll
  for (int i = 0; i < 4; ++i) {
    const int ar = wm * 64 + i * 16 + l15;
    abase[i] = ar * 128 + (((ar & 7) << 4) ^ (h << 4));
    const int br = wn * 64 + i * 16 + l15;
    bbase[i] = br * 128 + (((br & 7) << 4) ^ (h << 4));
  }

  stage(0, 0);
  const int NT = K >> 6;
  #pragma unroll 1
  for (int t = 0; t < NT; ++t) {
    const int cur = t & 1;
    if (t + 1 < NT) {
      stage(cur ^ 1, (t + 1) << 6);
      asm volatile("s_waitcnt vmcnt(8)" ::: "memory");
    } else {
      asm volatile("s_waitcnt vmcnt(0)" ::: "memory");
    }
    __builtin_amdgcn_sched_barrier(0);
    __builtin_amdgcn_s_barrier();
    __builtin_amdgcn_sched_barrier(0);

    const char* cA = (const char*)sA[cur];
    const char* cB = (const char*)sB[cur];
    #pragma unroll
    for (int kk = 0; kk < 2; ++kk) {
      bf16x8 af[4], bfr[4];
      #pragma unroll
      for (int m = 0; m < 4; ++m)
        af[m] = *reinterpret_cast<const bf16x8*>(cA + (abase[m] ^ (kk << 6)));
      #pragma unroll
      for (int n = 0; n < 4; ++n)
        bfr[n] = *reinterpret_cast<const bf16x8*>(cB + (bbase[n] ^ (kk << 6)));
      #pragma unroll
      for (int m = 0; m < 4; ++m)
        #pragma unroll
        for (int n = 0; n < 4; ++n)
          acc[m][n] = __builtin_amdgcn_mfma_f32_16x16x32_bf16(af[m], bfr[n], acc[m][n], 0, 0, 0);
    }
    __builtin_amdgcn_sched_barrier(0);
    __builtin_amdgcn_s_barrier();
    __builtin_amdgcn_sched_barrier(0);
  }

  float* outf = (float*)Cout;
  unsigned short* outh = (unsigned short*)Cout;
  const size_t cb = (size_t)b * sCb;

  if constexpr (EXPOUT) {
    #pragma unroll
    for (int m = 0; m < 4; ++m) {
      #pragma unroll
      for (int r = 0; r < 4; ++r) {
        const int row = bm * 128 + wm * 64 + m * 16 + h * 4 + r;
        float se = 0.f;
        #pragma unroll
        for (int n = 0; n < 4; ++n) {
          const int col = bn * 128 + wn * 64 + n * 16 + l15;
          unsigned short pb = f2bf(__expf(fminf(acc[m][n][r] * scale, 80.f)));
          outh[cb + (size_t)row * N + col] = pb;
          se += bf2f(pb);
        }
        #pragma unroll
        for (int msk = 1; msk <= 8; msk <<= 1) se += __shfl_xor(se, msk);
        if (l15 == 0)
          part_out[(((size_t)b * NSP + row) << 6) + bn * 2 + wn] = se;
      }
    }
    return;
  }

  #pragma unroll
  for (int m = 0; m < 4; ++m) {
    #pragma unroll
    for (int r = 0; r < 4; ++r) {
      const int row = bm * 128 + wm * 64 + m * 16 + h * 4 + r;
      float invl = 1.0f;
      if constexpr (INVL) invl = invl_in[(size_t)b * NSP + row];
      #pragma unroll
      for (int n = 0; n < 4; ++n) {
        const int col = bn * 128 + wn * 64 + n * 16 + l15;
        float vv = acc[m][n][r];
        if constexpr (BIAS == 1) vv += bias[row];
        if constexpr (BIAS == 2) vv += bias[col];
        vv *= scale;
        if constexpr (INVL) vv *= invl;
        if constexpr (RESID) vv += resid[(size_t)b * sRb + (size_t)row * N + col];
        const size_t oi = cb + (size_t)row * N + col;
        if constexpr (OBF16) outh[oi] = f2bf(vv);
        else outf[oi] = vv;
      }
    }
  }
}

extern "C" void kernel_launch(void* const* d_in, const int* in_sizes, int n_in,
                              void* d_out, int out_size, void* d_ws, size_t ws_size,
                              hipStream_t stream) {
  const float* x    = (const float*)d_in[0];
  const float* gn_w = (const float*)d_in[1];
  const float* gn_b = (const float*)d_in[2];
  const float* wq   = (const float*)d_in[3];
  const float* bq   = (const float*)d_in[4];
  const float* wk   = (const float*)d_in[5];
  const float* bk   = (const float*)d_in[6];
  const float* wv   = (const float*)d_in[7];
  const float* bv   = (const float*)d_in[8];
  const float* wo   = (const float*)d_in[9];
  const float* bo   = (const float*)d_in[10];
  float* out = (float*)d_out;

  char* ws = (char*)d_ws;
  const size_t NC = (size_t)NSP * CC;           // 2M elems
  unsigned short* wqk_bf = (unsigned short*)ws; // [1024][512] 1 MiB
  unsigned short* wv_bf  = wqk_bf + 524288;
  unsigned short* wo_bf  = wv_bf + 262144;
  float* bias_qk = (float*)(wo_bf + 262144);    // [1024]
  unsigned short* xnT = (unsigned short*)(bias_qk + 1024);  // [B][N][C] 16 MiB
  unsigned short* qkT = xnT + NB * NC;          // [B][N][1024] 32 MiB (q scaled | k)
  unsigned short* vC  = qkT + NB * NC * 2;      // [B][C][N] 16 MiB
  unsigned short* aoutT = vC + NB * NC;         // [B][N][C] 16 MiB
  unsigned short* S = aoutT + NB * NC;          // [B][N][N] bf16 P_unnorm 128 MiB
  float* part = (float*)(S + (size_t)NB * NSP * NSP);  // [B*N][64] 4 MiB
  float* invl = part + ((size_t)NB * NSP << 6);        // [B*N]

  const float scale = 0.04419417382415922f;  // 512^-0.5
  const size_t SS = (size_t)NSP * NSP;
  const long long sQK = (long long)NSP * 1024;

  cvt_w_kernel<<<1024, 256, 0, stream>>>(wq, wk, wv, wo, bq, bk,
                                         wqk_bf, wv_bf, wo_bf, bias_qk, scale);
  gn_kernel<<<NB * NGRP, 256, 0, stream>>>(x, gn_w, gn_b, xnT);

  // qkT[b][n][0..1023] = xnT.wqk^T + bias_qk  (q half pre-scaled)
  gemm2<2, true, false, false, false, false><<<dim3(1024 / 128, NSP / 128, NB), 256, 0, stream>>>(
      xnT, wqk_bf, bias_qk, nullptr, qkT, nullptr, nullptr,
      NSP, 1024, CC, CC, CC, 1.0f, NC, 0, sQK, 0);
  // vC[o,i] = wv.xnT^T + bv
  gemm2<1, true, false, false, false, false><<<dim3(NSP / 128, CC / 128, NB), 256, 0, stream>>>(
      wv_bf, xnT, bv, nullptr, vC, nullptr, nullptr,
      CC, NSP, CC, CC, CC, 1.0f, 0, NC, NC, 0);

  // P_unnorm = exp(q.k^T) bf16 + per-row partial sums (square XCD chunking)
  gemm2<0, true, false, true, false, true><<<dim3(NSP / 128, NSP / 128, NB), 256, 0, stream>>>(
      qkT, qkT + 512, nullptr, nullptr, S, nullptr, part,
      NSP, NSP, CC, 1024, 1024, 1.0f, sQK, sQK, (long long)SS, 0);
  sum_reduce_kernel<<<NB * NSP / 4, 256, 0, stream>>>(part, invl);
  // aoutT = (P_unnorm . V) * (1/l)
  gemm2<0, true, false, false, true, false><<<dim3(CC / 128, NSP / 128, NB), 256, 0, stream>>>(
      S, vC, nullptr, nullptr, aoutT, invl, nullptr,
      NSP, CC, NSP, NSP, NSP, 1.0f, SS, NC, NC, 0);

  // out = wo.aoutT^T + bo + x
  gemm2<1, false, true, false, false, false><<<dim3(NSP / 128, CC / 128, NB), 256, 0, stream>>>(
      wo_bf, aoutT, bo, x, out, nullptr, nullptr,
      CC, NSP, CC, CC, CC, 1.0f, 0, NC, NC, NC);
}

// Round 12
// 292.192 us; speedup vs baseline: 1.1355x; 1.1355x over previous
//
#include <hip/hip_runtime.h>

#define NB 4
#define CC 512
#define NSP 4096
#define NGRP 32

using bf16x8 = __attribute__((ext_vector_type(8))) __bf16;
using f32x4  = __attribute__((ext_vector_type(4))) float;

__device__ __forceinline__ unsigned short f2bf(float f) {
  union { float f; unsigned int u; } v; v.f = f;
  unsigned int r = v.u + 0x7fffu + ((v.u >> 16) & 1u);
  return (unsigned short)(r >> 16);
}
__device__ __forceinline__ float bf2f(unsigned short h) {
  union { unsigned int u; float f; } v; v.u = ((unsigned int)h) << 16;
  return v.f;
}

// ---------------- weights fp32 -> bf16 (wq pre-scaled), bias_qk ----------------
__global__ __launch_bounds__(256) void cvt_w_kernel(const float* __restrict__ wq,
    const float* __restrict__ wk, const float* __restrict__ wv,
    const float* __restrict__ wo, const float* __restrict__ bq,
    const float* __restrict__ bk, unsigned short* __restrict__ wqk,
    unsigned short* __restrict__ wv_bf, unsigned short* __restrict__ wo_bf,
    float* __restrict__ bias_qk, float scale) {
  int i = blockIdx.x * 256 + threadIdx.x;  // covers 512*512
  wqk[i]          = f2bf(wq[i] * scale);
  wqk[i + 262144] = f2bf(wk[i]);
  wv_bf[i] = f2bf(wv[i]);
  wo_bf[i] = f2bf(wo[i]);
  if (i < 512)        bias_qk[i] = bq[i] * scale;
  else if (i < 1024)  bias_qk[i] = bk[i - 512];
}

// ---------------- GroupNorm stats ----------------
__global__ __launch_bounds__(256) void gn_stats_kernel(const float* __restrict__ x,
                                                       float* __restrict__ stats) {
  const int b = blockIdx.x >> 5, g = blockIdx.x & 31;
  const float4* p = reinterpret_cast<const float4*>(x + ((size_t)b * CC + g * 16) * NSP);
  float s = 0.f, ss = 0.f;
  for (int i = threadIdx.x; i < 16384; i += 256) {
    float4 v = p[i];
    s  += v.x + v.y + v.z + v.w;
    ss += v.x * v.x + v.y * v.y + v.z * v.z + v.w * v.w;
  }
  __shared__ float rs[4], rss[4];
  #pragma unroll
  for (int o = 32; o >= 1; o >>= 1) { s += __shfl_down(s, o); ss += __shfl_down(ss, o); }
  if ((threadIdx.x & 63) == 0) { rs[threadIdx.x >> 6] = s; rss[threadIdx.x >> 6] = ss; }
  __syncthreads();
  if (threadIdx.x == 0) {
    s = rs[0] + rs[1] + rs[2] + rs[3];
    ss = rss[0] + rss[1] + rss[2] + rss[3];
    float mean = s * (1.f / 65536.f);
    float var = ss * (1.f / 65536.f) - mean * mean;
    stats[blockIdx.x * 2 + 0] = mean;
    stats[blockIdx.x * 2 + 1] = rsqrtf(var + 1e-6f);
  }
}

// ---------------- GN apply + transpose to xnT [B][N][C] bf16 ----------------
__global__ __launch_bounds__(256) void gn_apply_kernel(const float* __restrict__ x,
    const float* __restrict__ stats, const float* __restrict__ gw,
    const float* __restrict__ gb, unsigned short* __restrict__ xnT) {
  const int b = blockIdx.z, c0 = blockIdx.y * 32, n0 = blockIdx.x * 32;
  __shared__ unsigned short tile[32][33];
  const int tx = threadIdx.x & 31, ty = threadIdx.x >> 5;
  #pragma unroll
  for (int r = 0; r < 4; ++r) {
    const int cl = ty + r * 8;
    const int c = c0 + cl;
    const int g = c >> 4;
    const float mean = stats[(b * 32 + g) * 2];
    const float rstd = stats[(b * 32 + g) * 2 + 1];
    const float sc = rstd * gw[c];
    const float sh = gb[c] - mean * sc;
    const float v = x[((size_t)b * CC + c) * NSP + n0 + tx];
    tile[cl][tx] = f2bf(v * sc + sh);
  }
  __syncthreads();
  #pragma unroll
  for (int r = 0; r < 4; ++r) {
    const int nl = ty + r * 8;
    xnT[((size_t)b * NSP + n0 + nl) * CC + c0 + tx] = tile[tx][nl];
  }
}

// ---------------- sum 64 partials -> 1/l per row ----------------
__global__ __launch_bounds__(256) void sum_reduce_kernel(const float* __restrict__ part,
                                                         float* __restrict__ invl) {
  const int row = blockIdx.x * 4 + (threadIdx.x >> 6);
  const int lane = threadIdx.x & 63;
  float v = part[((size_t)row << 6) + lane];
  #pragma unroll
  for (int msk = 1; msk <= 32; msk <<= 1) v += __shfl_xor(v, msk);
  if (lane == 0) invl[row] = 1.f / v;
}

// ---------------- 128^2 MFMA GEMM (bf16) ----------------
// OMODE 0: fp32 out. 1: bf16 out. 2: bf16 EXPOUT exp(min(acc*scale,80)) + row sums.
// 3: qk-split bf16 (N=1024, halves to Cout/Cout2, ld 512).
// BIAS 0/1(row)/2(col). RESID adds resid. INVL multiplies by invl_in[row].
template<int BIAS, int OMODE, bool RESID, bool INVL>
__global__ __launch_bounds__(256) void gemm2(
    const unsigned short* __restrict__ A, const unsigned short* __restrict__ B,
    const float* __restrict__ bias, const float* __restrict__ resid,
    void* __restrict__ Cout, void* __restrict__ Cout2,
    const float* __restrict__ invl_in, float* __restrict__ part_out,
    int M, int N, int K, float scale,
    long long sAb, long long sBb, long long sCb, long long sRb) {
  __shared__ __align__(16) unsigned short sA[2][128 * 64];
  __shared__ __align__(16) unsigned short sB[2][128 * 64];
  const int tid = threadIdx.x;
  const int lane = tid & 63;
  const int wid  = tid >> 6;

  const unsigned nwg = gridDim.x * gridDim.y * gridDim.z;
  unsigned lin = blockIdx.x + gridDim.x * (blockIdx.y + gridDim.y * blockIdx.z);
  lin = (lin & 7) * (nwg >> 3) + (lin >> 3);
  const int bn = lin % gridDim.x;
  const unsigned t2 = lin / gridDim.x;
  const int bm = t2 % gridDim.y;
  const int b  = t2 / gridDim.y;

  const unsigned short* Ab = A + (size_t)b * sAb + (size_t)bm * 128 * K;
  const unsigned short* Bb = B + (size_t)b * sBb + (size_t)bn * 128 * K;
  const int wm = wid >> 1, wn = wid & 1;
  const int l15 = lane & 15, h = lane >> 4;

  f32x4 acc[4][4] = {};

  auto stage = [&](int buf, int k0) {
    #pragma unroll
    for (int it = 0; it < 4; ++it) {
      const int o  = (it * 256 + tid) * 16;
      const int r  = o >> 7;
      const int c2 = (o & 127) ^ ((r & 7) << 4);
      __builtin_amdgcn_global_load_lds(
          (const __attribute__((address_space(1))) void*)((const char*)(Ab + (size_t)r * K + k0) + c2),
          (__attribute__((address_space(3))) void*)((char*)sA[buf] + o), 16, 0, 0);
      __builtin_amdgcn_global_load_lds(
          (const __attribute__((address_space(1))) void*)((const char*)(Bb + (size_t)r * K + k0) + c2),
          (__attribute__((address_space(3))) void*)((char*)sB[buf] + o), 16, 0, 0);
    }
  };

  int abase[4], bbase[4];
  #pragma unroll
  for (int i = 0; i < 4; ++i) {
    const int ar = wm * 64 + i * 16 + l15;
    abase[i] = ar * 128 + (((ar & 7) << 4) ^ (h << 4));
    const int br = wn * 64 + i * 16 + l15;
    bbase[i] = br * 128 + (((br & 7) << 4) ^ (h << 4));
  }

  stage(0, 0);
  const int NT = K >> 6;
  #pragma unroll 1
  for (int t = 0; t < NT; ++t) {
    const int cur = t & 1;
    if (t + 1 < NT) {
      stage(cur ^ 1, (t + 1) << 6);
      asm volatile("s_waitcnt vmcnt(8)" ::: "memory");
    } else {
      asm volatile("s_waitcnt vmcnt(0)" ::: "memory");
    }
    __builtin_amdgcn_sched_barrier(0);
    __builtin_amdgcn_s_barrier();
    __builtin_amdgcn_sched_barrier(0);

    const char* cA = (const char*)sA[cur];
    const char* cB = (const char*)sB[cur];
    #pragma unroll
    for (int kk = 0; kk < 2; ++kk) {
      bf16x8 af[4], bfr[4];
      #pragma unroll
      for (int m = 0; m < 4; ++m)
        af[m] = *reinterpret_cast<const bf16x8*>(cA + (abase[m] ^ (kk << 6)));
      #pragma unroll
      for (int n = 0; n < 4; ++n)
        bfr[n] = *reinterpret_cast<const bf16x8*>(cB + (bbase[n] ^ (kk << 6)));
      #pragma unroll
      for (int m = 0; m < 4; ++m)
        #pragma unroll
        for (int n = 0; n < 4; ++n)
          acc[m][n] = __builtin_amdgcn_mfma_f32_16x16x32_bf16(af[m], bfr[n], acc[m][n], 0, 0, 0);
    }
    __builtin_amdgcn_sched_barrier(0);
    __builtin_amdgcn_s_barrier();
    __builtin_amdgcn_sched_barrier(0);
  }

  const size_t cb = (size_t)b * sCb;

  if constexpr (OMODE == 2) {
    unsigned short* outh = (unsigned short*)Cout;
    #pragma unroll
    for (int m = 0; m < 4; ++m) {
      #pragma unroll
      for (int r = 0; r < 4; ++r) {
        const int row = bm * 128 + wm * 64 + m * 16 + h * 4 + r;
        float se = 0.f;
        #pragma unroll
        for (int n = 0; n < 4; ++n) {
          const int col = bn * 128 + wn * 64 + n * 16 + l15;
          unsigned short pb = f2bf(__expf(fminf(acc[m][n][r] * scale, 80.f)));
          outh[cb + (size_t)row * N + col] = pb;
          se += bf2f(pb);
        }
        #pragma unroll
        for (int msk = 1; msk <= 8; msk <<= 1) se += __shfl_xor(se, msk);
        if (l15 == 0)
          part_out[(((size_t)b * NSP + row) << 6) + bn * 2 + wn] = se;
      }
    }
    return;
  }

  #pragma unroll
  for (int m = 0; m < 4; ++m) {
    #pragma unroll
    for (int r = 0; r < 4; ++r) {
      const int row = bm * 128 + wm * 64 + m * 16 + h * 4 + r;
      float il = 1.0f;
      if constexpr (INVL) il = invl_in[(size_t)b * NSP + row];
      #pragma unroll
      for (int n = 0; n < 4; ++n) {
        const int col = bn * 128 + wn * 64 + n * 16 + l15;
        float vv = acc[m][n][r];
        if constexpr (BIAS == 1) vv += bias[row];
        if constexpr (BIAS == 2) vv += bias[col];
        vv *= scale;
        if constexpr (INVL) vv *= il;
        if constexpr (RESID) vv += resid[(size_t)b * sRb + (size_t)row * N + col];
        if constexpr (OMODE == 0) {
          ((float*)Cout)[cb + (size_t)row * N + col] = vv;
        } else if constexpr (OMODE == 1) {
          ((unsigned short*)Cout)[cb + (size_t)row * N + col] = f2bf(vv);
        } else {  // OMODE == 3: qk split
          unsigned short* dst = (col < 512) ? (unsigned short*)Cout : (unsigned short*)Cout2;
          dst[cb + (size_t)row * 512 + (col & 511)] = f2bf(vv);
        }
      }
    }
  }
}

extern "C" void kernel_launch(void* const* d_in, const int* in_sizes, int n_in,
                              void* d_out, int out_size, void* d_ws, size_t ws_size,
                              hipStream_t stream) {
  const float* x    = (const float*)d_in[0];
  const float* gn_w = (const float*)d_in[1];
  const float* gn_b = (const float*)d_in[2];
  const float* wq   = (const float*)d_in[3];
  const float* bq   = (const float*)d_in[4];
  const float* wk   = (const float*)d_in[5];
  const float* bk   = (const float*)d_in[6];
  const float* wv   = (const float*)d_in[7];
  const float* bv   = (const float*)d_in[8];
  const float* wo   = (const float*)d_in[9];
  const float* bo   = (const float*)d_in[10];
  float* out = (float*)d_out;

  char* ws = (char*)d_ws;
  const size_t NC = (size_t)NSP * CC;              // 2M elems
  unsigned short* wqk_bf = (unsigned short*)ws;    // [1024][512] 1 MiB
  unsigned short* wv_bf  = wqk_bf + 524288;
  unsigned short* wo_bf  = wv_bf + 262144;
  float* bias_qk = (float*)(wo_bf + 262144);       // [1024]
  float* gstats  = bias_qk + 1024;                 // [B*32][2]
  unsigned short* xnT = (unsigned short*)(gstats + 512);  // [B][N][C]
  unsigned short* qT  = xnT + NB * NC;             // [B][N][C] pre-scaled
  unsigned short* kT  = qT + NB * NC;
  unsigned short* vC  = kT + NB * NC;              // [B][C][N] bf16
  unsigned short* aoutT = vC + NB * NC;            // [B][N][C]
  unsigned short* S = aoutT + NB * NC;             // [B][N][N] bf16 P_unnorm 128 MiB
  float* part = (float*)(S + (size_t)NB * NSP * NSP);      // [B*N][64] 4 MiB
  float* invl = part + ((size_t)NB * NSP << 6);            // [B*N]

  const float scale = 0.04419417382415922f;  // 512^-0.5
  const long long SS = (long long)NSP * NSP;

  cvt_w_kernel<<<1024, 256, 0, stream>>>(wq, wk, wv, wo, bq, bk,
                                         wqk_bf, wv_bf, wo_bf, bias_qk, scale);
  gn_stats_kernel<<<NB * NGRP, 256, 0, stream>>>(x, gstats);
  gn_apply_kernel<<<dim3(NSP / 32, CC / 32, NB), 256, 0, stream>>>(x, gstats, gn_w, gn_b, xnT);

  // fused qk: [q*scale | k] = xnT.wqk^T + bias_qk, split to contiguous qT/kT (ld 512)
  gemm2<2, 3, false, false><<<dim3(1024 / 128, NSP / 128, NB), 256, 0, stream>>>(
      xnT, wqk_bf, bias_qk, nullptr, qT, kT, nullptr, nullptr,
      NSP, 1024, CC, 1.0f, NC, 0, NC, 0);
  // vC[c][n] = wv.xnT^T + bv  (bf16)
  gemm2<1, 1, false, false><<<dim3(NSP / 128, CC / 128, NB), 256, 0, stream>>>(
      wv_bf, xnT, bv, nullptr, vC, nullptr, nullptr, nullptr,
      CC, NSP, CC, 1.0f, 0, NC, NC, 0);

  // S = exp(q.k^T) bf16 P_unnorm + per-row partial sums
  gemm2<0, 2, false, false><<<dim3(NSP / 128, NSP / 128, NB), 256, 0, stream>>>(
      qT, kT, nullptr, nullptr, S, nullptr, nullptr, part,
      NSP, NSP, CC, 1.0f, NC, NC, SS, 0);
  sum_reduce_kernel<<<NB * NSP / 4, 256, 0, stream>>>(part, invl);
  // aoutT = (P_unnorm . V) * invl
  gemm2<0, 1, false, true><<<dim3(CC / 128, NSP / 128, NB), 256, 0, stream>>>(
      S, vC, nullptr, nullptr, aoutT, nullptr, invl, nullptr,
      NSP, CC, NSP, 1.0f, SS, NC, NC, 0);

  // out = wo.aoutT^T + bo + x
  gemm2<1, 0, true, false><<<dim3(NSP / 128, CC / 128, NB), 256, 0, stream>>>(
      wo_bf, aoutT, bo, x, out, nullptr, nullptr, nullptr,
      CC, NSP, CC, 1.0f, 0, NC, NC, NC);
}

// Round 13
// 280.254 us; speedup vs baseline: 1.1839x; 1.0426x over previous
//
#include <hip/hip_runtime.h>

#define NB 4
#define CC 512
#define NSP 4096
#define NGRP 32

using bf16x8 = __attribute__((ext_vector_type(8))) __bf16;
using f32x4  = __attribute__((ext_vector_type(4))) float;

__device__ __forceinline__ unsigned short f2bf(float f) {
  union { float f; unsigned int u; } v; v.f = f;
  unsigned int r = v.u + 0x7fffu + ((v.u >> 16) & 1u);
  return (unsigned short)(r >> 16);
}
__device__ __forceinline__ float bf2f(unsigned short h) {
  union { unsigned int u; float f; } v; v.u = ((unsigned int)h) << 16;
  return v.f;
}

// ---------------- weights fp32 -> bf16 (wq pre-scaled), bias_qk ----------------
__global__ __launch_bounds__(256) void cvt_w_kernel(const float* __restrict__ wq,
    const float* __restrict__ wk, const float* __restrict__ wv,
    const float* __restrict__ wo, const float* __restrict__ bq,
    const float* __restrict__ bk, unsigned short* __restrict__ wqk,
    unsigned short* __restrict__ wv_bf, unsigned short* __restrict__ wo_bf,
    float* __restrict__ bias_qk, float scale) {
  int i = blockIdx.x * 256 + threadIdx.x;
  wqk[i]          = f2bf(wq[i] * scale);
  wqk[i + 262144] = f2bf(wk[i]);
  wv_bf[i] = f2bf(wv[i]);
  wo_bf[i] = f2bf(wo[i]);
  if (i < 512)        bias_qk[i] = bq[i] * scale;
  else if (i < 1024)  bias_qk[i] = bk[i - 512];
}

// ---------------- GroupNorm stats ----------------
__global__ __launch_bounds__(256) void gn_stats_kernel(const float* __restrict__ x,
                                                       float* __restrict__ stats) {
  const int b = blockIdx.x >> 5, g = blockIdx.x & 31;
  const float4* p = reinterpret_cast<const float4*>(x + ((size_t)b * CC + g * 16) * NSP);
  float s = 0.f, ss = 0.f;
  for (int i = threadIdx.x; i < 16384; i += 256) {
    float4 v = p[i];
    s  += v.x + v.y + v.z + v.w;
    ss += v.x * v.x + v.y * v.y + v.z * v.z + v.w * v.w;
  }
  __shared__ float rs[4], rss[4];
  #pragma unroll
  for (int o = 32; o >= 1; o >>= 1) { s += __shfl_down(s, o); ss += __shfl_down(ss, o); }
  if ((threadIdx.x & 63) == 0) { rs[threadIdx.x >> 6] = s; rss[threadIdx.x >> 6] = ss; }
  __syncthreads();
  if (threadIdx.x == 0) {
    s = rs[0] + rs[1] + rs[2] + rs[3];
    ss = rss[0] + rss[1] + rss[2] + rss[3];
    float mean = s * (1.f / 65536.f);
    float var = ss * (1.f / 65536.f) - mean * mean;
    stats[blockIdx.x * 2 + 0] = mean;
    stats[blockIdx.x * 2 + 1] = rsqrtf(var + 1e-6f);
  }
}

// ---------------- GN apply + transpose to xnT [B][N][C] bf16 ----------------
__global__ __launch_bounds__(256) void gn_apply_kernel(const float* __restrict__ x,
    const float* __restrict__ stats, const float* __restrict__ gw,
    const float* __restrict__ gb, unsigned short* __restrict__ xnT) {
  const int b = blockIdx.z, c0 = blockIdx.y * 32, n0 = blockIdx.x * 32;
  __shared__ unsigned short tile[32][33];
  const int tx = threadIdx.x & 31, ty = threadIdx.x >> 5;
  #pragma unroll
  for (int r = 0; r < 4; ++r) {
    const int cl = ty + r * 8;
    const int c = c0 + cl;
    const int g = c >> 4;
    const float mean = stats[(b * 32 + g) * 2];
    const float rstd = stats[(b * 32 + g) * 2 + 1];
    const float sc = rstd * gw[c];
    const float sh = gb[c] - mean * sc;
    const float v = x[((size_t)b * CC + c) * NSP + n0 + tx];
    tile[cl][tx] = f2bf(v * sc + sh);
  }
  __syncthreads();
  #pragma unroll
  for (int r = 0; r < 4; ++r) {
    const int nl = ty + r * 8;
    xnT[((size_t)b * NSP + n0 + nl) * CC + c0 + tx] = tile[tx][nl];
  }
}

// ---------------- sum 64 partials -> 1/l per row ----------------
__global__ __launch_bounds__(256) void sum_reduce_kernel(const float* __restrict__ part,
                                                         float* __restrict__ invl) {
  const int row = blockIdx.x * 4 + (threadIdx.x >> 6);
  const int lane = threadIdx.x & 63;
  float v = part[((size_t)row << 6) + lane];
  #pragma unroll
  for (int msk = 1; msk <= 32; msk <<= 1) v += __shfl_xor(v, msk);
  if (lane == 0) invl[row] = 1.f / v;
}

// ---------------- 128^2 MFMA GEMM (small GEMMs: qkv / proj) ----------------
// OMODE 0: fp32 out. 1: bf16 out. 3: qk-split bf16 (N=1024, halves to Cout/Cout2).
template<int BIAS, int OMODE, bool RESID>
__global__ __launch_bounds__(256) void gemm2(
    const unsigned short* __restrict__ A, const unsigned short* __restrict__ B,
    const float* __restrict__ bias, const float* __restrict__ resid,
    void* __restrict__ Cout, void* __restrict__ Cout2,
    int M, int N, int K, float scale,
    long long sAb, long long sBb, long long sCb, long long sRb) {
  __shared__ __align__(16) unsigned short sA[2][128 * 64];
  __shared__ __align__(16) unsigned short sB[2][128 * 64];
  const int tid = threadIdx.x;
  const int lane = tid & 63;
  const int wid  = tid >> 6;

  const unsigned nwg = gridDim.x * gridDim.y * gridDim.z;
  unsigned lin = blockIdx.x + gridDim.x * (blockIdx.y + gridDim.y * blockIdx.z);
  lin = (lin & 7) * (nwg >> 3) + (lin >> 3);
  const int bn = lin % gridDim.x;
  const unsigned t2 = lin / gridDim.x;
  const int bm = t2 % gridDim.y;
  const int b  = t2 / gridDim.y;

  const unsigned short* Ab = A + (size_t)b * sAb + (size_t)bm * 128 * K;
  const unsigned short* Bb = B + (size_t)b * sBb + (size_t)bn * 128 * K;
  const int wm = wid >> 1, wn = wid & 1;
  const int l15 = lane & 15, h = lane >> 4;

  f32x4 acc[4][4] = {};

  auto stage = [&](int buf, int k0) {
    #pragma unroll
    for (int it = 0; it < 4; ++it) {
      const int o  = (it * 256 + tid) * 16;
      const int r  = o >> 7;
      const int c2 = (o & 127) ^ ((r & 7) << 4);
      __builtin_amdgcn_global_load_lds(
          (const __attribute__((address_space(1))) void*)((const char*)(Ab + (size_t)r * K + k0) + c2),
          (__attribute__((address_space(3))) void*)((char*)sA[buf] + o), 16, 0, 0);
      __builtin_amdgcn_global_load_lds(
          (const __attribute__((address_space(1))) void*)((const char*)(Bb + (size_t)r * K + k0) + c2),
          (__attribute__((address_space(3))) void*)((char*)sB[buf] + o), 16, 0, 0);
    }
  };

  int abase[4], bbase[4];
  #pragma unroll
  for (int i = 0; i < 4; ++i) {
    const int ar = wm * 64 + i * 16 + l15;
    abase[i] = ar * 128 + (((ar & 7) << 4) ^ (h << 4));
    const int br = wn * 64 + i * 16 + l15;
    bbase[i] = br * 128 + (((br & 7) << 4) ^ (h << 4));
  }

  stage(0, 0);
  const int NT = K >> 6;
  #pragma unroll 1
  for (int t = 0; t < NT; ++t) {
    const int cur = t & 1;
    if (t + 1 < NT) {
      stage(cur ^ 1, (t + 1) << 6);
      asm volatile("s_waitcnt vmcnt(8)" ::: "memory");
    } else {
      asm volatile("s_waitcnt vmcnt(0)" ::: "memory");
    }
    __builtin_amdgcn_sched_barrier(0);
    __builtin_amdgcn_s_barrier();
    __builtin_amdgcn_sched_barrier(0);

    const char* cA = (const char*)sA[cur];
    const char* cB = (const char*)sB[cur];
    #pragma unroll
    for (int kk = 0; kk < 2; ++kk) {
      bf16x8 af[4], bfr[4];
      #pragma unroll
      for (int m = 0; m < 4; ++m)
        af[m] = *reinterpret_cast<const bf16x8*>(cA + (abase[m] ^ (kk << 6)));
      #pragma unroll
      for (int n = 0; n < 4; ++n)
        bfr[n] = *reinterpret_cast<const bf16x8*>(cB + (bbase[n] ^ (kk << 6)));
      #pragma unroll
      for (int m = 0; m < 4; ++m)
        #pragma unroll
        for (int n = 0; n < 4; ++n)
          acc[m][n] = __builtin_amdgcn_mfma_f32_16x16x32_bf16(af[m], bfr[n], acc[m][n], 0, 0, 0);
    }
    __builtin_amdgcn_sched_barrier(0);
    __builtin_amdgcn_s_barrier();
    __builtin_amdgcn_sched_barrier(0);
  }

  const size_t cb = (size_t)b * sCb;
  #pragma unroll
  for (int m = 0; m < 4; ++m) {
    #pragma unroll
    for (int r = 0; r < 4; ++r) {
      const int row = bm * 128 + wm * 64 + m * 16 + h * 4 + r;
      #pragma unroll
      for (int n = 0; n < 4; ++n) {
        const int col = bn * 128 + wn * 64 + n * 16 + l15;
        float vv = acc[m][n][r];
        if constexpr (BIAS == 1) vv += bias[row];
        if constexpr (BIAS == 2) vv += bias[col];
        vv *= scale;
        if constexpr (RESID) vv += resid[(size_t)b * sRb + (size_t)row * N + col];
        if constexpr (OMODE == 0) {
          ((float*)Cout)[cb + (size_t)row * N + col] = vv;
        } else if constexpr (OMODE == 1) {
          ((unsigned short*)Cout)[cb + (size_t)row * N + col] = f2bf(vv);
        } else {  // qk split
          unsigned short* dst = (col < 512) ? (unsigned short*)Cout : (unsigned short*)Cout2;
          dst[cb + (size_t)row * 512 + (col & 511)] = f2bf(vv);
        }
      }
    }
  }
}

// ---------------- 8-phase 256-row MFMA GEMM (m201-style, big attention GEMMs) ----
// BM=256, 512 threads, 8 waves (WMs x 8/WMs). per-wave (256/WMs) x 64 out.
// Per 2-K-tile iteration: M_REP phases, each {ds_read subtile; stage 1 half-tile;
// barrier; lgkm(0); setprio(1); 16 MFMA; setprio(0); [counted vmcnt]; barrier}.
// Stage order: A(u+1)->buf1, B(u+2)->buf0, A(u+2)->buf0, B(u+3)->buf1.
// vmcnt(2*BH) at both half-iteration ends (FIFO-verified); vmcnt(0) in last iter.
// OMODE 2: expout bf16 P=exp(min(acc,80)) + per-row 64-slot partial sums.
// OMODE 1: bf16 out, scaled by invl_in[row].
template<int BN, int WMs, int OMODE>
__global__ __launch_bounds__(512) void gemm8p(
    const unsigned short* __restrict__ A, const unsigned short* __restrict__ B,
    void* __restrict__ Cout, const float* __restrict__ invl_in,
    float* __restrict__ part_out, int N, int K, int lda, int ldb,
    long long sAb, long long sBb, long long sCb) {
  constexpr int WNs = 8 / WMs;
  constexpr int WR = 256 / WMs;      // per-wave rows
  constexpr int M_REP = WR / 16;     // 8 (S) or 4 (PV)
  constexpr int BH = BN / 128;       // B half-tiles per K-tile (2 or 1)
  __shared__ __align__(16) unsigned short sA[2][256 * 64];
  __shared__ __align__(16) unsigned short sB[2][BN * 64];
  const int tid = threadIdx.x;
  const int lane = tid & 63;
  const int wid  = tid >> 6;

  const unsigned nwg = gridDim.x * gridDim.y * gridDim.z;
  unsigned lin = blockIdx.x + gridDim.x * (blockIdx.y + gridDim.y * blockIdx.z);
  lin = (lin & 7) * (nwg >> 3) + (lin >> 3);
  const int bn = lin % gridDim.x;
  const unsigned t2 = lin / gridDim.x;
  const int bm = t2 % gridDim.y;
  const int b  = t2 / gridDim.y;

  const unsigned short* Ab = A + (size_t)b * sAb + (size_t)bm * 256 * lda;
  const unsigned short* Bb = B + (size_t)b * sBb + (size_t)bn * BN * ldb;
  const int wm = wid / WNs, wn = wid % WNs;
  const int l15 = lane & 15, h = lane >> 4;

  // stage one 128x64 half-tile (2 gloads/thread), linear LDS + inv-swizzled src
  auto stage_half = [&](const unsigned short* gbase, int ld, int k0, unsigned short* lbase) {
    #pragma unroll
    for (int it = 0; it < 2; ++it) {
      const int o = (it * 512 + tid) * 16;
      const int r = o >> 7;
      const int c2 = (o & 127) ^ ((r & 7) << 4);
      __builtin_amdgcn_global_load_lds(
          (const __attribute__((address_space(1))) void*)((const char*)(gbase + (size_t)r * ld + k0) + c2),
          (__attribute__((address_space(3))) void*)((char*)lbase + o), 16, 0, 0);
    }
  };
  auto stageA = [&](int buf, int kt) {  // both halves when called with hs loop outside
    stage_half(Ab, lda, kt << 6, &sA[buf][0]);
  };
  (void)stageA;

  int abase[M_REP], bbase[4];
  #pragma unroll
  for (int i = 0; i < M_REP; ++i) {
    const int ar = wm * WR + i * 16 + l15;
    abase[i] = ar * 128 + (((ar & 7) << 4) ^ (h << 4));
  }
  #pragma unroll
  for (int i = 0; i < 4; ++i) {
    const int br = wn * 64 + i * 16 + l15;
    bbase[i] = br * 128 + (((br & 7) << 4) ^ (h << 4));
  }

  f32x4 acc[M_REP][4] = {};
  const int NT = K >> 6;   // even, >= 4

  // ---- prologue: tile0 (A+B) -> buf0, B(1) -> buf1; retire tile0, keep B(1) ----
  stage_half(Ab, lda, 0, &sA[0][0]);
  stage_half(Ab + (size_t)128 * lda, lda, 0, &sA[0][128 * 64]);
  #pragma unroll
  for (int hs = 0; hs < BH; ++hs)
    stage_half(Bb + (size_t)hs * 128 * ldb, ldb, 0, &sB[0][hs * 128 * 64]);
  #pragma unroll
  for (int hs = 0; hs < BH; ++hs)
    stage_half(Bb + (size_t)hs * 128 * ldb, ldb, 64, &sB[1][hs * 128 * 64]);
  if constexpr (BH == 2) asm volatile("s_waitcnt vmcnt(4)" ::: "memory");
  else                   asm volatile("s_waitcnt vmcnt(2)" ::: "memory");
  __builtin_amdgcn_sched_barrier(0);
  __builtin_amdgcn_s_barrier();
  __builtin_amdgcn_sched_barrier(0);

  #pragma unroll 1
  for (int u = 0; u < NT; u += 2) {
    const bool lastit = (u + 2 >= NT);
    #pragma unroll
    for (int half = 0; half < 2; ++half) {
      const char* cA = (const char*)sA[half];
      const char* cB = (const char*)sB[half];
      bf16x8 bfr[2][4];
      #pragma unroll
      for (int p = 0; p < M_REP / 2; ++p) {
        if (p == 0) {
          #pragma unroll
          for (int kk = 0; kk < 2; ++kk)
            #pragma unroll
            for (int n = 0; n < 4; ++n)
              bfr[kk][n] = *reinterpret_cast<const bf16x8*>(cB + (bbase[n] ^ (kk << 6)));
        }
        bf16x8 af[2][2];
        #pragma unroll
        for (int i = 0; i < 2; ++i)
          #pragma unroll
          for (int kk = 0; kk < 2; ++kk)
            af[kk][i] = *reinterpret_cast<const bf16x8*>(cA + (abase[2 * p + i] ^ (kk << 6)));

        // ---- per-phase staging (schedule verified by FIFO sim, see header) ----
        const int ph = half * (M_REP / 2) + p;
        if constexpr (M_REP == 8) {
          if (ph == 0)      stage_half(Ab, lda, (u + 1) << 6, &sA[1][0]);
          else if (ph == 1) stage_half(Ab + (size_t)128 * lda, lda, (u + 1) << 6, &sA[1][128 * 64]);
          else if (ph == 2) { if (u + 2 < NT) stage_half(Bb, ldb, (u + 2) << 6, &sB[0][0]); }
          else if (ph == 3) { if (u + 2 < NT) stage_half(Bb + (size_t)128 * ldb, ldb, (u + 2) << 6, &sB[0][128 * 64]); }
          else if (ph == 4) { if (u + 2 < NT) stage_half(Ab, lda, (u + 2) << 6, &sA[0][0]); }
          else if (ph == 5) { if (u + 2 < NT) stage_half(Ab + (size_t)128 * lda, lda, (u + 2) << 6, &sA[0][128 * 64]); }
          else if (ph == 6) { if (u + 3 < NT) stage_half(Bb, ldb, (u + 3) << 6, &sB[1][0]); }
          else              { if (u + 3 < NT) stage_half(Bb + (size_t)128 * ldb, ldb, (u + 3) << 6, &sB[1][128 * 64]); }
        } else {  // M_REP == 4 (PV): BH == 1
          if (ph == 0) {
            stage_half(Ab, lda, (u + 1) << 6, &sA[1][0]);
            stage_half(Ab + (size_t)128 * lda, lda, (u + 1) << 6, &sA[1][128 * 64]);
          } else if (ph == 1) {
            if (u + 2 < NT) stage_half(Bb, ldb, (u + 2) << 6, &sB[0][0]);
          } else if (ph == 2) {
            if (u + 2 < NT) {
              stage_half(Ab, lda, (u + 2) << 6, &sA[0][0]);
              stage_half(Ab + (size_t)128 * lda, lda, (u + 2) << 6, &sA[0][128 * 64]);
            }
          } else {
            if (u + 3 < NT) stage_half(Bb, ldb, (u + 3) << 6, &sB[1][0]);
          }
        }

        __builtin_amdgcn_sched_barrier(0);
        __builtin_amdgcn_s_barrier();
        __builtin_amdgcn_sched_barrier(0);
        asm volatile("s_waitcnt lgkmcnt(0)" ::: "memory");
        __builtin_amdgcn_sched_barrier(0);
        __builtin_amdgcn_s_setprio(1);
        #pragma unroll
        for (int i = 0; i < 2; ++i)
          #pragma unroll
          for (int n = 0; n < 4; ++n)
            #pragma unroll
            for (int kk = 0; kk < 2; ++kk)
              acc[2 * p + i][n] = __builtin_amdgcn_mfma_f32_16x16x32_bf16(
                  af[kk][i], bfr[kk][n], acc[2 * p + i][n], 0, 0, 0);
        __builtin_amdgcn_s_setprio(0);
        __builtin_amdgcn_sched_barrier(0);
        if (p == M_REP / 2 - 1) {   // half-iteration end: counted vmcnt
          if (half == 0) {
            if (lastit) asm volatile("s_waitcnt vmcnt(0)" ::: "memory");
            else if constexpr (BH == 2) asm volatile("s_waitcnt vmcnt(4)" ::: "memory");
            else                        asm volatile("s_waitcnt vmcnt(2)" ::: "memory");
          } else if (!lastit) {
            if constexpr (BH == 2) asm volatile("s_waitcnt vmcnt(4)" ::: "memory");
            else                   asm volatile("s_waitcnt vmcnt(2)" ::: "memory");
          }
          __builtin_amdgcn_sched_barrier(0);
        }
        __builtin_amdgcn_s_barrier();
        __builtin_amdgcn_sched_barrier(0);
      }
    }
  }

  const size_t cb = (size_t)b * sCb;
  if constexpr (OMODE == 2) {
    unsigned short* outh = (unsigned short*)Cout;
    #pragma unroll
    for (int m = 0; m < M_REP; ++m) {
      #pragma unroll
      for (int r = 0; r < 4; ++r) {
        const int row = bm * 256 + wm * WR + m * 16 + h * 4 + r;
        float se = 0.f;
        #pragma unroll
        for (int n = 0; n < 4; ++n) {
          const int col = bn * BN + wn * 64 + n * 16 + l15;
          unsigned short pb = f2bf(__expf(fminf(acc[m][n][r], 80.f)));
          outh[cb + (size_t)row * N + col] = pb;
          se += bf2f(pb);
        }
        #pragma unroll
        for (int msk = 1; msk <= 8; msk <<= 1) se += __shfl_xor(se, msk);
        if (l15 == 0)
          part_out[(((size_t)b * NSP + row) << 6) + bn * (BN / 64) + wn] = se;
      }
    }
  } else {
    unsigned short* outh = (unsigned short*)Cout;
    #pragma unroll
    for (int m = 0; m < M_REP; ++m) {
      #pragma unroll
      for (int r = 0; r < 4; ++r) {
        const int row = bm * 256 + wm * WR + m * 16 + h * 4 + r;
        const float il = invl_in[(size_t)b * NSP + row];
        #pragma unroll
        for (int n = 0; n < 4; ++n) {
          const int col = bn * BN + wn * 64 + n * 16 + l15;
          outh[cb + (size_t)row * N + col] = f2bf(acc[m][n][r] * il);
        }
      }
    }
  }
}

extern "C" void kernel_launch(void* const* d_in, const int* in_sizes, int n_in,
                              void* d_out, int out_size, void* d_ws, size_t ws_size,
                              hipStream_t stream) {
  const float* x    = (const float*)d_in[0];
  const float* gn_w = (const float*)d_in[1];
  const float* gn_b = (const float*)d_in[2];
  const float* wq   = (const float*)d_in[3];
  const float* bq   = (const float*)d_in[4];
  const float* wk   = (const float*)d_in[5];
  const float* bk   = (const float*)d_in[6];
  const float* wv   = (const float*)d_in[7];
  const float* bv   = (const float*)d_in[8];
  const float* wo   = (const float*)d_in[9];
  const float* bo   = (const float*)d_in[10];
  float* out = (float*)d_out;

  char* ws = (char*)d_ws;
  const size_t NC = (size_t)NSP * CC;
  unsigned short* wqk_bf = (unsigned short*)ws;
  unsigned short* wv_bf  = wqk_bf + 524288;
  unsigned short* wo_bf  = wv_bf + 262144;
  float* bias_qk = (float*)(wo_bf + 262144);
  float* gstats  = bias_qk + 1024;
  unsigned short* xnT = (unsigned short*)(gstats + 512);  // [B][N][C]
  unsigned short* qT  = xnT + NB * NC;                    // pre-scaled
  unsigned short* kT  = qT + NB * NC;
  unsigned short* vC  = kT + NB * NC;                     // [B][C][N]
  unsigned short* aoutT = vC + NB * NC;
  unsigned short* S = aoutT + NB * NC;                    // [B][N][N] bf16 P_unnorm
  float* part = (float*)(S + (size_t)NB * NSP * NSP);     // [B*N][64]
  float* invl = part + ((size_t)NB * NSP << 6);

  const float scale = 0.04419417382415922f;  // 512^-0.5
  const long long SS = (long long)NSP * NSP;

  cvt_w_kernel<<<1024, 256, 0, stream>>>(wq, wk, wv, wo, bq, bk,
                                         wqk_bf, wv_bf, wo_bf, bias_qk, scale);
  gn_stats_kernel<<<NB * NGRP, 256, 0, stream>>>(x, gstats);
  gn_apply_kernel<<<dim3(NSP / 32, CC / 32, NB), 256, 0, stream>>>(x, gstats, gn_w, gn_b, xnT);

  // fused qk: [q*scale | k] = xnT.wqk^T + bias_qk -> contiguous qT/kT (ld 512)
  gemm2<2, 3, false><<<dim3(1024 / 128, NSP / 128, NB), 256, 0, stream>>>(
      xnT, wqk_bf, bias_qk, nullptr, qT, kT, NSP, 1024, CC, 1.0f, NC, 0, NC, 0);
  // vC[c][n] = wv.xnT^T + bv
  gemm2<1, 1, false><<<dim3(NSP / 128, CC / 128, NB), 256, 0, stream>>>(
      wv_bf, xnT, bv, nullptr, vC, nullptr, CC, NSP, CC, 1.0f, 0, NC, NC, 0);

  // S = exp(q.k^T) bf16 P_unnorm + per-row partial sums (8-phase 256^2)
  gemm8p<256, 2, 2><<<dim3(NSP / 256, NSP / 256, NB), 512, 0, stream>>>(
      qT, kT, S, nullptr, part, NSP, CC, CC, CC, NC, NC, SS);
  sum_reduce_kernel<<<NB * NSP / 4, 256, 0, stream>>>(part, invl);
  // aoutT = (P_unnorm . V) * invl   (4-phase 256x128, grid = 256 WGs)
  gemm8p<128, 4, 1><<<dim3(CC / 128, NSP / 256, NB), 512, 0, stream>>>(
      S, vC, aoutT, invl, nullptr, CC, NSP, NSP, NSP, SS, NC, NC);

  // out = wo.aoutT^T + bo + x
  gemm2<1, 0, true><<<dim3(NSP / 128, CC / 128, NB), 256, 0, stream>>>(
      wo_bf, aoutT, bo, x, out, nullptr, CC, NSP, CC, 1.0f, 0, NC, NC, NC);
}

// Round 14
// 277.875 us; speedup vs baseline: 1.1940x; 1.0086x over previous
//
#include <hip/hip_runtime.h>

#define NB 4
#define CC 512
#define NSP 4096
#define NGRP 32

using bf16x8 = __attribute__((ext_vector_type(8))) __bf16;
using f32x4  = __attribute__((ext_vector_type(4))) float;

__device__ __forceinline__ unsigned short f2bf(float f) {
  union { float f; unsigned int u; } v; v.f = f;
  unsigned int r = v.u + 0x7fffu + ((v.u >> 16) & 1u);
  return (unsigned short)(r >> 16);
}
__device__ __forceinline__ float bf2f(unsigned short h) {
  union { unsigned int u; float f; } v; v.u = ((unsigned int)h) << 16;
  return v.f;
}

// ---------------- weights fp32 -> bf16 (wq pre-scaled), bias_qk ----------------
__global__ __launch_bounds__(256) void cvt_w_kernel(const float* __restrict__ wq,
    const float* __restrict__ wk, const float* __restrict__ wv,
    const float* __restrict__ wo, const float* __restrict__ bq,
    const float* __restrict__ bk, unsigned short* __restrict__ wqk,
    unsigned short* __restrict__ wv_bf, unsigned short* __restrict__ wo_bf,
    float* __restrict__ bias_qk, float scale) {
  int i = blockIdx.x * 256 + threadIdx.x;
  wqk[i]          = f2bf(wq[i] * scale);
  wqk[i + 262144] = f2bf(wk[i]);
  wv_bf[i] = f2bf(wv[i]);
  wo_bf[i] = f2bf(wo[i]);
  if (i < 512)        bias_qk[i] = bq[i] * scale;
  else if (i < 1024)  bias_qk[i] = bk[i - 512];
}

// ---------------- GroupNorm stats ----------------
__global__ __launch_bounds__(256) void gn_stats_kernel(const float* __restrict__ x,
                                                       float* __restrict__ stats) {
  const int b = blockIdx.x >> 5, g = blockIdx.x & 31;
  const float4* p = reinterpret_cast<const float4*>(x + ((size_t)b * CC + g * 16) * NSP);
  float s = 0.f, ss = 0.f;
  for (int i = threadIdx.x; i < 16384; i += 256) {
    float4 v = p[i];
    s  += v.x + v.y + v.z + v.w;
    ss += v.x * v.x + v.y * v.y + v.z * v.z + v.w * v.w;
  }
  __shared__ float rs[4], rss[4];
  #pragma unroll
  for (int o = 32; o >= 1; o >>= 1) { s += __shfl_down(s, o); ss += __shfl_down(ss, o); }
  if ((threadIdx.x & 63) == 0) { rs[threadIdx.x >> 6] = s; rss[threadIdx.x >> 6] = ss; }
  __syncthreads();
  if (threadIdx.x == 0) {
    s = rs[0] + rs[1] + rs[2] + rs[3];
    ss = rss[0] + rss[1] + rss[2] + rss[3];
    float mean = s * (1.f / 65536.f);
    float var = ss * (1.f / 65536.f) - mean * mean;
    stats[blockIdx.x * 2 + 0] = mean;
    stats[blockIdx.x * 2 + 1] = rsqrtf(var + 1e-6f);
  }
}

// ---------------- GN apply + transpose to xnT [B][N][C] bf16 ----------------
__global__ __launch_bounds__(256) void gn_apply_kernel(const float* __restrict__ x,
    const float* __restrict__ stats, const float* __restrict__ gw,
    const float* __restrict__ gb, unsigned short* __restrict__ xnT) {
  const int b = blockIdx.z, c0 = blockIdx.y * 32, n0 = blockIdx.x * 32;
  __shared__ unsigned short tile[32][33];
  const int tx = threadIdx.x & 31, ty = threadIdx.x >> 5;
  #pragma unroll
  for (int r = 0; r < 4; ++r) {
    const int cl = ty + r * 8;
    const int c = c0 + cl;
    const int g = c >> 4;
    const float mean = stats[(b * 32 + g) * 2];
    const float rstd = stats[(b * 32 + g) * 2 + 1];
    const float sc = rstd * gw[c];
    const float sh = gb[c] - mean * sc;
    const float v = x[((size_t)b * CC + c) * NSP + n0 + tx];
    tile[cl][tx] = f2bf(v * sc + sh);
  }
  __syncthreads();
  #pragma unroll
  for (int r = 0; r < 4; ++r) {
    const int nl = ty + r * 8;
    xnT[((size_t)b * NSP + n0 + nl) * CC + c0 + tx] = tile[tx][nl];
  }
}

// ---------------- sum 64 partials -> 1/l per row ----------------
__global__ __launch_bounds__(256) void sum_reduce_kernel(const float* __restrict__ part,
                                                         float* __restrict__ invl) {
  const int row = blockIdx.x * 4 + (threadIdx.x >> 6);
  const int lane = threadIdx.x & 63;
  float v = part[((size_t)row << 6) + lane];
  #pragma unroll
  for (int msk = 1; msk <= 32; msk <<= 1) v += __shfl_xor(v, msk);
  if (lane == 0) invl[row] = 1.f / v;
}

// ---------------- 128^2 MFMA GEMM (small GEMMs: qkv / proj) ----------------
// OMODE 0: fp32 out. 1: bf16 out. 3: qk-split bf16 (N=1024, halves to Cout/Cout2).
template<int BIAS, int OMODE, bool RESID>
__global__ __launch_bounds__(256) void gemm2(
    const unsigned short* __restrict__ A, const unsigned short* __restrict__ B,
    const float* __restrict__ bias, const float* __restrict__ resid,
    void* __restrict__ Cout, void* __restrict__ Cout2,
    int M, int N, int K, float scale,
    long long sAb, long long sBb, long long sCb, long long sRb) {
  __shared__ __align__(16) unsigned short sA[2][128 * 64];
  __shared__ __align__(16) unsigned short sB[2][128 * 64];
  const int tid = threadIdx.x;
  const int lane = tid & 63;
  const int wid  = tid >> 6;

  const unsigned nwg = gridDim.x * gridDim.y * gridDim.z;
  unsigned lin = blockIdx.x + gridDim.x * (blockIdx.y + gridDim.y * blockIdx.z);
  lin = (lin & 7) * (nwg >> 3) + (lin >> 3);
  const int bn = lin % gridDim.x;
  const unsigned t2 = lin / gridDim.x;
  const int bm = t2 % gridDim.y;
  const int b  = t2 / gridDim.y;

  const unsigned short* Ab = A + (size_t)b * sAb + (size_t)bm * 128 * K;
  const unsigned short* Bb = B + (size_t)b * sBb + (size_t)bn * 128 * K;
  const int wm = wid >> 1, wn = wid & 1;
  const int l15 = lane & 15, h = lane >> 4;

  f32x4 acc[4][4] = {};

  auto stage = [&](int buf, int k0) {
    #pragma unroll
    for (int it = 0; it < 4; ++it) {
      const int o  = (it * 256 + tid) * 16;
      const int r  = o >> 7;
      const int c2 = (o & 127) ^ ((r & 7) << 4);
      __builtin_amdgcn_global_load_lds(
          (const __attribute__((address_space(1))) void*)((const char*)(Ab + (size_t)r * K + k0) + c2),
          (__attribute__((address_space(3))) void*)((char*)sA[buf] + o), 16, 0, 0);
      __builtin_amdgcn_global_load_lds(
          (const __attribute__((address_space(1))) void*)((const char*)(Bb + (size_t)r * K + k0) + c2),
          (__attribute__((address_space(3))) void*)((char*)sB[buf] + o), 16, 0, 0);
    }
  };

  int abase[4], bbase[4];
  #pragma unroll
  for (int i = 0; i < 4; ++i) {
    const int ar = wm * 64 + i * 16 + l15;
    abase[i] = ar * 128 + (((ar & 7) << 4) ^ (h << 4));
    const int br = wn * 64 + i * 16 + l15;
    bbase[i] = br * 128 + (((br & 7) << 4) ^ (h << 4));
  }

  stage(0, 0);
  const int NT = K >> 6;
  #pragma unroll 1
  for (int t = 0; t < NT; ++t) {
    const int cur = t & 1;
    if (t + 1 < NT) {
      stage(cur ^ 1, (t + 1) << 6);
      asm volatile("s_waitcnt vmcnt(8)" ::: "memory");
    } else {
      asm volatile("s_waitcnt vmcnt(0)" ::: "memory");
    }
    __builtin_amdgcn_sched_barrier(0);
    __builtin_amdgcn_s_barrier();
    __builtin_amdgcn_sched_barrier(0);

    const char* cA = (const char*)sA[cur];
    const char* cB = (const char*)sB[cur];
    #pragma unroll
    for (int kk = 0; kk < 2; ++kk) {
      bf16x8 af[4], bfr[4];
      #pragma unroll
      for (int m = 0; m < 4; ++m)
        af[m] = *reinterpret_cast<const bf16x8*>(cA + (abase[m] ^ (kk << 6)));
      #pragma unroll
      for (int n = 0; n < 4; ++n)
        bfr[n] = *reinterpret_cast<const bf16x8*>(cB + (bbase[n] ^ (kk << 6)));
      #pragma unroll
      for (int m = 0; m < 4; ++m)
        #pragma unroll
        for (int n = 0; n < 4; ++n)
          acc[m][n] = __builtin_amdgcn_mfma_f32_16x16x32_bf16(af[m], bfr[n], acc[m][n], 0, 0, 0);
    }
    __builtin_amdgcn_sched_barrier(0);
    __builtin_amdgcn_s_barrier();
    __builtin_amdgcn_sched_barrier(0);
  }

  const size_t cb = (size_t)b * sCb;
  #pragma unroll
  for (int m = 0; m < 4; ++m) {
    #pragma unroll
    for (int r = 0; r < 4; ++r) {
      const int row = bm * 128 + wm * 64 + m * 16 + h * 4 + r;
      #pragma unroll
      for (int n = 0; n < 4; ++n) {
        const int col = bn * 128 + wn * 64 + n * 16 + l15;
        float vv = acc[m][n][r];
        if constexpr (BIAS == 1) vv += bias[row];
        if constexpr (BIAS == 2) vv += bias[col];
        vv *= scale;
        if constexpr (RESID) vv += resid[(size_t)b * sRb + (size_t)row * N + col];
        if constexpr (OMODE == 0) {
          ((float*)Cout)[cb + (size_t)row * N + col] = vv;
        } else if constexpr (OMODE == 1) {
          ((unsigned short*)Cout)[cb + (size_t)row * N + col] = f2bf(vv);
        } else {  // qk split
          unsigned short* dst = (col < 512) ? (unsigned short*)Cout : (unsigned short*)Cout2;
          dst[cb + (size_t)row * 512 + (col & 511)] = f2bf(vv);
        }
      }
    }
  }
}

// ---------------- 8-phase 256-row MFMA GEMM (m201-style, de-pinned) ----------------
// Per phase: {ds_reads; stage 1 half-tile; s_barrier; lgkmcnt(0); setprio(1);
// 16 MFMA; setprio(0); [counted vmcnt at half-iter end]; s_barrier}. No sched_barriers
// (m141: order-pinning costs ~40%). vmcnt counts FIFO-verified in R12 (passed).
template<int BN, int WMs, int OMODE>
__global__ __launch_bounds__(512) void gemm8p(
    const unsigned short* __restrict__ A, const unsigned short* __restrict__ B,
    void* __restrict__ Cout, const float* __restrict__ invl_in,
    float* __restrict__ part_out, int N, int K, int lda, int ldb,
    long long sAb, long long sBb, long long sCb) {
  constexpr int WNs = 8 / WMs;
  constexpr int WR = 256 / WMs;      // per-wave rows
  constexpr int M_REP = WR / 16;     // 8 (S) or 4 (PV)
  constexpr int BH = BN / 128;       // B half-tiles per K-tile (2 or 1)
  __shared__ __align__(16) unsigned short sA[2][256 * 64];
  __shared__ __align__(16) unsigned short sB[2][BN * 64];
  const int tid = threadIdx.x;
  const int lane = tid & 63;
  const int wid  = tid >> 6;

  const unsigned nwg = gridDim.x * gridDim.y * gridDim.z;
  unsigned lin = blockIdx.x + gridDim.x * (blockIdx.y + gridDim.y * blockIdx.z);
  lin = (lin & 7) * (nwg >> 3) + (lin >> 3);
  const int bn = lin % gridDim.x;
  const unsigned t2 = lin / gridDim.x;
  const int bm = t2 % gridDim.y;
  const int b  = t2 / gridDim.y;

  const unsigned short* Ab = A + (size_t)b * sAb + (size_t)bm * 256 * lda;
  const unsigned short* Bb = B + (size_t)b * sBb + (size_t)bn * BN * ldb;
  const int wm = wid / WNs, wn = wid % WNs;
  const int l15 = lane & 15, h = lane >> 4;

  auto stage_half = [&](const unsigned short* gbase, int ld, int k0, unsigned short* lbase) {
    #pragma unroll
    for (int it = 0; it < 2; ++it) {
      const int o = (it * 512 + tid) * 16;
      const int r = o >> 7;
      const int c2 = (o & 127) ^ ((r & 7) << 4);
      __builtin_amdgcn_global_load_lds(
          (const __attribute__((address_space(1))) void*)((const char*)(gbase + (size_t)r * ld + k0) + c2),
          (__attribute__((address_space(3))) void*)((char*)lbase + o), 16, 0, 0);
    }
  };

  int abase[M_REP], bbase[4];
  #pragma unroll
  for (int i = 0; i < M_REP; ++i) {
    const int ar = wm * WR + i * 16 + l15;
    abase[i] = ar * 128 + (((ar & 7) << 4) ^ (h << 4));
  }
  #pragma unroll
  for (int i = 0; i < 4; ++i) {
    const int br = wn * 64 + i * 16 + l15;
    bbase[i] = br * 128 + (((br & 7) << 4) ^ (h << 4));
  }

  f32x4 acc[M_REP][4] = {};
  const int NT = K >> 6;   // even, >= 4

  // ---- prologue: tile0 (A+B) -> buf0, B(1) -> buf1 ----
  stage_half(Ab, lda, 0, &sA[0][0]);
  stage_half(Ab + (size_t)128 * lda, lda, 0, &sA[0][128 * 64]);
  #pragma unroll
  for (int hs = 0; hs < BH; ++hs)
    stage_half(Bb + (size_t)hs * 128 * ldb, ldb, 0, &sB[0][hs * 128 * 64]);
  #pragma unroll
  for (int hs = 0; hs < BH; ++hs)
    stage_half(Bb + (size_t)hs * 128 * ldb, ldb, 64, &sB[1][hs * 128 * 64]);
  if constexpr (BH == 2) asm volatile("s_waitcnt vmcnt(4)" ::: "memory");
  else                   asm volatile("s_waitcnt vmcnt(2)" ::: "memory");
  __builtin_amdgcn_s_barrier();

  #pragma unroll 1
  for (int u = 0; u < NT; u += 2) {
    const bool lastit = (u + 2 >= NT);
    #pragma unroll
    for (int half = 0; half < 2; ++half) {
      const char* cA = (const char*)sA[half];
      const char* cB = (const char*)sB[half];
      bf16x8 bfr[2][4];
      #pragma unroll
      for (int p = 0; p < M_REP / 2; ++p) {
        if (p == 0) {
          #pragma unroll
          for (int kk = 0; kk < 2; ++kk)
            #pragma unroll
            for (int n = 0; n < 4; ++n)
              bfr[kk][n] = *reinterpret_cast<const bf16x8*>(cB + (bbase[n] ^ (kk << 6)));
        }
        bf16x8 af[2][2];
        #pragma unroll
        for (int i = 0; i < 2; ++i)
          #pragma unroll
          for (int kk = 0; kk < 2; ++kk)
            af[kk][i] = *reinterpret_cast<const bf16x8*>(cA + (abase[2 * p + i] ^ (kk << 6)));

        // ---- per-phase staging: A(u+1)->buf1, B(u+2)->buf0, A(u+2)->buf0, B(u+3)->buf1
        const int ph = half * (M_REP / 2) + p;
        if constexpr (M_REP == 8) {
          if (ph == 0)      stage_half(Ab, lda, (u + 1) << 6, &sA[1][0]);
          else if (ph == 1) stage_half(Ab + (size_t)128 * lda, lda, (u + 1) << 6, &sA[1][128 * 64]);
          else if (ph == 2) { if (u + 2 < NT) stage_half(Bb, ldb, (u + 2) << 6, &sB[0][0]); }
          else if (ph == 3) { if (u + 2 < NT) stage_half(Bb + (size_t)128 * ldb, ldb, (u + 2) << 6, &sB[0][128 * 64]); }
          else if (ph == 4) { if (u + 2 < NT) stage_half(Ab, lda, (u + 2) << 6, &sA[0][0]); }
          else if (ph == 5) { if (u + 2 < NT) stage_half(Ab + (size_t)128 * lda, lda, (u + 2) << 6, &sA[0][128 * 64]); }
          else if (ph == 6) { if (u + 3 < NT) stage_half(Bb, ldb, (u + 3) << 6, &sB[1][0]); }
          else              { if (u + 3 < NT) stage_half(Bb + (size_t)128 * ldb, ldb, (u + 3) << 6, &sB[1][128 * 64]); }
        } else {  // M_REP == 4 (PV): BH == 1
          if (ph == 0) {
            stage_half(Ab, lda, (u + 1) << 6, &sA[1][0]);
            stage_half(Ab + (size_t)128 * lda, lda, (u + 1) << 6, &sA[1][128 * 64]);
          } else if (ph == 1) {
            if (u + 2 < NT) stage_half(Bb, ldb, (u + 2) << 6, &sB[0][0]);
          } else if (ph == 2) {
            if (u + 2 < NT) {
              stage_half(Ab, lda, (u + 2) << 6, &sA[0][0]);
              stage_half(Ab + (size_t)128 * lda, lda, (u + 2) << 6, &sA[0][128 * 64]);
            }
          } else {
            if (u + 3 < NT) stage_half(Bb, ldb, (u + 3) << 6, &sB[1][0]);
          }
        }

        __builtin_amdgcn_s_barrier();
        asm volatile("s_waitcnt lgkmcnt(0)");
        __builtin_amdgcn_s_setprio(1);
        #pragma unroll
        for (int i = 0; i < 2; ++i)
          #pragma unroll
          for (int n = 0; n < 4; ++n)
            #pragma unroll
            for (int kk = 0; kk < 2; ++kk)
              acc[2 * p + i][n] = __builtin_amdgcn_mfma_f32_16x16x32_bf16(
                  af[kk][i], bfr[kk][n], acc[2 * p + i][n], 0, 0, 0);
        __builtin_amdgcn_s_setprio(0);
        if (p == M_REP / 2 - 1) {   // half-iteration end: counted vmcnt
          if (half == 0) {
            if (lastit) asm volatile("s_waitcnt vmcnt(0)" ::: "memory");
            else if constexpr (BH == 2) asm volatile("s_waitcnt vmcnt(4)" ::: "memory");
            else                        asm volatile("s_waitcnt vmcnt(2)" ::: "memory");
          } else if (!lastit) {
            if constexpr (BH == 2) asm volatile("s_waitcnt vmcnt(4)" ::: "memory");
            else                   asm volatile("s_waitcnt vmcnt(2)" ::: "memory");
          }
        }
        __builtin_amdgcn_s_barrier();
      }
    }
  }

  const size_t cb = (size_t)b * sCb;
  if constexpr (OMODE == 2) {
    unsigned short* outh = (unsigned short*)Cout;
    #pragma unroll
    for (int m = 0; m < M_REP; ++m) {
      #pragma unroll
      for (int r = 0; r < 4; ++r) {
        const int row = bm * 256 + wm * WR + m * 16 + h * 4 + r;
        float se = 0.f;
        #pragma unroll
        for (int n = 0; n < 4; ++n) {
          const int col = bn * BN + wn * 64 + n * 16 + l15;
          unsigned short pb = f2bf(__expf(fminf(acc[m][n][r], 80.f)));
          outh[cb + (size_t)row * N + col] = pb;
          se += bf2f(pb);
        }
        #pragma unroll
        for (int msk = 1; msk <= 8; msk <<= 1) se += __shfl_xor(se, msk);
        if (l15 == 0)
          part_out[(((size_t)b * NSP + row) << 6) + bn * (BN / 64) + wn] = se;
      }
    }
  } else {
    unsigned short* outh = (unsigned short*)Cout;
    #pragma unroll
    for (int m = 0; m < M_REP; ++m) {
      #pragma unroll
      for (int r = 0; r < 4; ++r) {
        const int row = bm * 256 + wm * WR + m * 16 + h * 4 + r;
        const float il = invl_in[(size_t)b * NSP + row];
        #pragma unroll
        for (int n = 0; n < 4; ++n) {
          const int col = bn * BN + wn * 64 + n * 16 + l15;
          outh[cb + (size_t)row * N + col] = f2bf(acc[m][n][r] * il);
        }
      }
    }
  }
}

extern "C" void kernel_launch(void* const* d_in, const int* in_sizes, int n_in,
                              void* d_out, int out_size, void* d_ws, size_t ws_size,
                              hipStream_t stream) {
  const float* x    = (const float*)d_in[0];
  const float* gn_w = (const float*)d_in[1];
  const float* gn_b = (const float*)d_in[2];
  const float* wq   = (const float*)d_in[3];
  const float* bq   = (const float*)d_in[4];
  const float* wk   = (const float*)d_in[5];
  const float* bk   = (const float*)d_in[6];
  const float* wv   = (const float*)d_in[7];
  const float* bv   = (const float*)d_in[8];
  const float* wo   = (const float*)d_in[9];
  const float* bo   = (const float*)d_in[10];
  float* out = (float*)d_out;

  char* ws = (char*)d_ws;
  const size_t NC = (size_t)NSP * CC;
  unsigned short* wqk_bf = (unsigned short*)ws;
  unsigned short* wv_bf  = wqk_bf + 524288;
  unsigned short* wo_bf  = wv_bf + 262144;
  float* bias_qk = (float*)(wo_bf + 262144);
  float* gstats  = bias_qk + 1024;
  unsigned short* xnT = (unsigned short*)(gstats + 512);  // [B][N][C]
  unsigned short* qT  = xnT + NB * NC;                    // pre-scaled
  unsigned short* kT  = qT + NB * NC;
  unsigned short* vC  = kT + NB * NC;                     // [B][C][N]
  unsigned short* aoutT = vC + NB * NC;
  unsigned short* S = aoutT + NB * NC;                    // [B][N][N] bf16 P_unnorm
  float* part = (float*)(S + (size_t)NB * NSP * NSP);     // [B*N][64]
  float* invl = part + ((size_t)NB * NSP << 6);

  const float scale = 0.04419417382415922f;  // 512^-0.5
  const long long SS = (long long)NSP * NSP;

  cvt_w_kernel<<<1024, 256, 0, stream>>>(wq, wk, wv, wo, bq, bk,
                                         wqk_bf, wv_bf, wo_bf, bias_qk, scale);
  gn_stats_kernel<<<NB * NGRP, 256, 0, stream>>>(x, gstats);
  gn_apply_kernel<<<dim3(NSP / 32, CC / 32, NB), 256, 0, stream>>>(x, gstats, gn_w, gn_b, xnT);

  // fused qk: [q*scale | k] = xnT.wqk^T + bias_qk -> contiguous qT/kT (ld 512)
  gemm2<2, 3, false><<<dim3(1024 / 128, NSP / 128, NB), 256, 0, stream>>>(
      xnT, wqk_bf, bias_qk, nullptr, qT, kT, NSP, 1024, CC, 1.0f, NC, 0, NC, 0);
  // vC[c][n] = wv.xnT^T + bv
  gemm2<1, 1, false><<<dim3(NSP / 128, CC / 128, NB), 256, 0, stream>>>(
      wv_bf, xnT, bv, nullptr, vC, nullptr, CC, NSP, CC, 1.0f, 0, NC, NC, 0);

  // S = exp(q.k^T) bf16 P_unnorm + per-row partial sums (8-phase 256^2)
  gemm8p<256, 2, 2><<<dim3(NSP / 256, NSP / 256, NB), 512, 0, stream>>>(
      qT, kT, S, nullptr, part, NSP, CC, CC, CC, NC, NC, SS);
  sum_reduce_kernel<<<NB * NSP / 4, 256, 0, stream>>>(part, invl);
  // aoutT = (P_unnorm . V) * invl   (4-phase 256x128, grid = 256 WGs)
  gemm8p<128, 4, 1><<<dim3(CC / 128, NSP / 256, NB), 512, 0, stream>>>(
      S, vC, aoutT, invl, nullptr, CC, NSP, NSP, NSP, SS, NC, NC);

  // out = wo.aoutT^T + bo + x
  gemm2<1, 0, true><<<dim3(NSP / 128, CC / 128, NB), 256, 0, stream>>>(
      wo_bf, aoutT, bo, x, out, nullptr, CC, NSP, CC, 1.0f, 0, NC, NC, NC);
}